// Round 17
// baseline (383.551 us; speedup 1.0000x reference)
//
#include <hip/hip_runtime.h>
#include <math.h>

#define NN 100000
#define NE 3200000
#define NG 512
#define PSHIFT 8
#define NPART ((NN + 255) >> 8)   // 391 partitions of 256 dst nodes
#define CHUNK 4096                // edges per binning block
#define HALF 50000                // src-half split: tb half = 3.2 MB (fits 4 MB XCD L2)
#define CAP 10240                 // fixed per-partition window (max expected ~8.5K)

typedef unsigned int uint;

__device__ inline uint bf16rne(float f) {
    uint u = __float_as_uint(f);
    return (u + 0x7fffu + ((u >> 16) & 1u)) >> 16;
}
__device__ inline float bf16lo(uint v) { return __uint_as_float(v << 16); }
__device__ inline float bf16hi(uint v) { return __uint_as_float(v & 0xffff0000u); }

// ---------------- init pcur (partition window bases) + pooled ----------------
__global__ void zero_misc_kernel(int* pcur, float* pooled) {
    int i = blockIdx.x * blockDim.x + threadIdx.x;
    if (i < NPART) pcur[i] = i * CAP;
    if (i < NG * 128) pooled[i] = 0.f;
}

// ---------------- part1: LDS-binned partition scatter into fixed-CAP windows ----------------
__global__ __launch_bounds__(256) void part1_kernel(
    const int* __restrict__ src, const int* __restrict__ dst,
    int* pcur, int* __restrict__ temp, int e) {
    __shared__ int cnt[NPART];
    __shared__ int gbase[NPART];
    int t = threadIdx.x;
    for (int i = t; i < NPART; i += 256) cnt[i] = 0;
    __syncthreads();
    int base = blockIdx.x * CHUNK;
    int pv[16], pp[16], rr[16];
#pragma unroll
    for (int j = 0; j < 16; j++) {
        int i = base + j * 256 + t;
        if (i < e) {
            int s = src[i], d = dst[i];
            pp[j] = d >> PSHIFT;
            pv[j] = (s << PSHIFT) | (d & 255);
            rr[j] = atomicAdd(&cnt[pp[j]], 1);
        } else {
            pp[j] = -1; pv[j] = 0; rr[j] = 0;
        }
    }
    __syncthreads();
    for (int i = t; i < NPART; i += 256)
        gbase[i] = cnt[i] ? atomicAdd(&pcur[i], cnt[i]) : 0;
    __syncthreads();
#pragma unroll
    for (int j = 0; j < 16; j++)
        if (pp[j] >= 0) temp[gbase[pp[j]] + rr[j]] = pv[j];
}

// ---------------- part2: per-partition A/B degree count + local scans + scatter ----------------
__global__ __launch_bounds__(256) void part2_kernel(
    const int* __restrict__ temp, const int* __restrict__ pcur,
    int* __restrict__ rowptrA, int* __restrict__ rowptrB, int* __restrict__ degpack,
    float* __restrict__ dinv, int* __restrict__ csr_src, int n) {
    __shared__ int cA[256], cB[256], sA[256], sB[256];
    __shared__ int totA_s;
    int p = blockIdx.x;
    int d0 = p << PSHIFT;
    int t = threadIdx.x;
    cA[t] = 0; cB[t] = 0;
    __syncthreads();
    int lo = p * CAP, hi = pcur[p];
    for (int i = lo + t; i < hi; i += 256) {
        int v = temp[i];
        if ((v >> PSHIFT) < HALF) atomicAdd(&cA[v & 255], 1);
        else atomicAdd(&cB[v & 255], 1);
    }
    __syncthreads();
    int degA = cA[t], degB = cB[t];
    sA[t] = degA; sB[t] = degB;
    __syncthreads();
    for (int off = 1; off < 256; off <<= 1) {
        int vA = (t >= off) ? sA[t - off] : 0;
        int vB = (t >= off) ? sB[t - off] : 0;
        __syncthreads();
        sA[t] += vA; sB[t] += vB;
        __syncthreads();
    }
    int exA = (t > 0) ? sA[t - 1] : 0;
    int exB = (t > 0) ? sB[t - 1] : 0;
    if (t == 255) totA_s = sA[255];
    __syncthreads();
    int bA = lo + exA;
    int bB = lo + totA_s + exB;
    int d = d0 + t;
    if (d < n) {
        rowptrA[d] = bA;
        rowptrB[d] = bB;
        degpack[d] = degA | (degB << 16);
        dinv[d] = rsqrtf((float)(degA + degB + 1));
    }
    __syncthreads();
    cA[t] = 0; cB[t] = 0;   // reuse as cursors
    sA[t] = bA; sB[t] = bB; // stable bases in LDS
    __syncthreads();
    for (int i = lo + t; i < hi; i += 256) {
        int v = temp[i];
        int ld = v & 255;
        int s = v >> PSHIFT;
        int slot;
        if (s < HALF) slot = sA[ld] + atomicAdd(&cA[ld], 1);
        else          slot = sB[ld] + atomicAdd(&cB[ld], 1);
        csr_src[slot] = s;
    }
}

// ---------------- tbs[n,32] (bf16) = (x[n,128] @ W[128,32]) * dinv[n] ----------------
__global__ __launch_bounds__(256) void gemm128_32_direct(
    const float* __restrict__ x, const float* __restrict__ W,
    const float* __restrict__ dinv, uint* __restrict__ tb, int n) {
    __shared__ float Wl[128 * 32];   // 16 KB only
    int t = threadIdx.x;
    for (int i = t; i < 128 * 32; i += 256) Wl[i] = W[i];
    __syncthreads();
    int tile0 = blockIdx.x * 128;
    int cg = t & 7, ng = t >> 3;
    int c0 = cg * 4;
    const float* xp[4];
    int nodev[4];
#pragma unroll
    for (int i = 0; i < 4; i++) {
        nodev[i] = tile0 + ng + 32 * i;
        xp[i] = x + (size_t)min(nodev[i], n - 1) * 128;
    }
    float acc[4][4];
#pragma unroll
    for (int i = 0; i < 4; i++)
        for (int j = 0; j < 4; j++) acc[i][j] = 0.f;
#pragma unroll 2
    for (int k4 = 0; k4 < 32; k4++) {
        float4 w0 = *(const float4*)&Wl[(k4 * 4 + 0) * 32 + c0];
        float4 w1 = *(const float4*)&Wl[(k4 * 4 + 1) * 32 + c0];
        float4 w2 = *(const float4*)&Wl[(k4 * 4 + 2) * 32 + c0];
        float4 w3 = *(const float4*)&Wl[(k4 * 4 + 3) * 32 + c0];
#pragma unroll
        for (int i = 0; i < 4; i++) {
            float4 xv = *(const float4*)&xp[i][k4 * 4];
            acc[i][0] += xv.x * w0.x + xv.y * w1.x + xv.z * w2.x + xv.w * w3.x;
            acc[i][1] += xv.x * w0.y + xv.y * w1.y + xv.z * w2.y + xv.w * w3.y;
            acc[i][2] += xv.x * w0.z + xv.y * w1.z + xv.z * w2.z + xv.w * w3.z;
            acc[i][3] += xv.x * w0.w + xv.y * w1.w + xv.z * w2.w + xv.w * w3.w;
        }
    }
#pragma unroll
    for (int i = 0; i < 4; i++) {
        if (nodev[i] < n) {
            float ds = dinv[nodev[i]];
            uint2 pk;
            pk.x = bf16rne(acc[i][0] * ds) | (bf16rne(acc[i][1] * ds) << 16);
            pk.y = bf16rne(acc[i][2] * ds) | (bf16rne(acc[i][3] * ds) << 16);
            *(uint2*)&tb[nodev[i] * 16 + cg * 2] = pk;
        }
    }
}

// ---------------- tbs[n,32] (bf16) = (xin[n,32] @ W[32,32]) * dinv[n] ----------------
__global__ __launch_bounds__(256) void gemm32_32_kernel(
    const float* __restrict__ xin, const float* __restrict__ W,
    const float* __restrict__ dinv, uint* __restrict__ tb, int n) {
    __shared__ float Wl[32 * 32];    // 4 KB
    __shared__ float Xl[128][36];    // 18.4 KB
    int t = threadIdx.x;
    for (int i = t; i < 32 * 32; i += 256) Wl[i] = W[i];
    int tile0 = blockIdx.x * 128;
    for (int idx = t; idx < 128 * 8; idx += 256) {
        int r = idx >> 3, q = idx & 7;
        int node = tile0 + r;
        float4 v = (node < n) ? *(const float4*)&xin[(size_t)node * 32 + q * 4]
                              : make_float4(0.f, 0.f, 0.f, 0.f);
        *(float4*)&Xl[r][q * 4] = v;
    }
    __syncthreads();
    int cg = t & 7, ng = t >> 3;
    int c0 = cg * 4;
    float acc[4][4];
#pragma unroll
    for (int i = 0; i < 4; i++)
        for (int j = 0; j < 4; j++) acc[i][j] = 0.f;
#pragma unroll
    for (int k4 = 0; k4 < 8; k4++) {
        float4 w0 = *(const float4*)&Wl[(k4 * 4 + 0) * 32 + c0];
        float4 w1 = *(const float4*)&Wl[(k4 * 4 + 1) * 32 + c0];
        float4 w2 = *(const float4*)&Wl[(k4 * 4 + 2) * 32 + c0];
        float4 w3 = *(const float4*)&Wl[(k4 * 4 + 3) * 32 + c0];
#pragma unroll
        for (int i = 0; i < 4; i++) {
            float4 xv = *(const float4*)&Xl[ng + 32 * i][k4 * 4];
            acc[i][0] += xv.x * w0.x + xv.y * w1.x + xv.z * w2.x + xv.w * w3.x;
            acc[i][1] += xv.x * w0.y + xv.y * w1.y + xv.z * w2.y + xv.w * w3.y;
            acc[i][2] += xv.x * w0.z + xv.y * w1.z + xv.z * w2.z + xv.w * w3.z;
            acc[i][3] += xv.x * w0.w + xv.y * w1.w + xv.z * w2.w + xv.w * w3.w;
        }
    }
#pragma unroll
    for (int i = 0; i < 4; i++) {
        int node = tile0 + ng + 32 * i;
        if (node < n) {
            float ds = dinv[node];
            uint2 pk;
            pk.x = bf16rne(acc[i][0] * ds) | (bf16rne(acc[i][1] * ds) << 16);
            pk.y = bf16rne(acc[i][2] * ds) | (bf16rne(acc[i][3] * ds) << 16);
            *(uint2*)&tb[node * 16 + cg * 2] = pk;
        }
    }
}

// ---------------- per-range accumulate (prescaled tb, 4-deep + tail) ----------------
__device__ inline void gath_range(int beg, int end, int sub, int f,
                                  const int* __restrict__ csr_src,
                                  const uint* __restrict__ tb,
                                  float& a0, float& a1, float& a2, float& a3) {
    int e = beg + sub;
    for (; e + 12 < end; e += 16) {
        int s0 = csr_src[e], s1 = csr_src[e + 4], s2 = csr_src[e + 8], s3 = csr_src[e + 12];
        uint2 v0 = *(const uint2*)&tb[s0 * 16 + f * 2];
        uint2 v1 = *(const uint2*)&tb[s1 * 16 + f * 2];
        uint2 v2 = *(const uint2*)&tb[s2 * 16 + f * 2];
        uint2 v3 = *(const uint2*)&tb[s3 * 16 + f * 2];
        a0 += bf16lo(v0.x) + bf16lo(v1.x) + bf16lo(v2.x) + bf16lo(v3.x);
        a1 += bf16hi(v0.x) + bf16hi(v1.x) + bf16hi(v2.x) + bf16hi(v3.x);
        a2 += bf16lo(v0.y) + bf16lo(v1.y) + bf16lo(v2.y) + bf16lo(v3.y);
        a3 += bf16hi(v0.y) + bf16hi(v1.y) + bf16hi(v2.y) + bf16hi(v3.y);
    }
    for (; e < end; e += 4) {
        int s = csr_src[e];
        uint2 v = *(const uint2*)&tb[s * 16 + f * 2];
        a0 += bf16lo(v.x); a1 += bf16hi(v.x);
        a2 += bf16lo(v.y); a3 += bf16hi(v.y);
    }
}

// ---------------- gather pass A: src<HALF edges -> f32 partial (L2-resident tb half) ----------------
__global__ __launch_bounds__(256) void gatherA_kernel(
    const int* __restrict__ rowptrA, const int* __restrict__ degpack,
    const int* __restrict__ csr_src, const uint* __restrict__ tb,
    float* __restrict__ xacc, int n) {
    int tid = blockIdx.x * blockDim.x + threadIdx.x;
    int node = tid >> 5;
    if (node >= n) return;
    int lane = tid & 31;
    int sub = lane >> 3, f = lane & 7;
    int beg = rowptrA[node];
    int end = beg + (degpack[node] & 0xFFFF);
    float a0 = 0.f, a1 = 0.f, a2 = 0.f, a3 = 0.f;
    gath_range(beg, end, sub, f, csr_src, tb, a0, a1, a2, a3);
    a0 += __shfl_xor(a0, 8, 64);  a1 += __shfl_xor(a1, 8, 64);
    a2 += __shfl_xor(a2, 8, 64);  a3 += __shfl_xor(a3, 8, 64);
    a0 += __shfl_xor(a0, 16, 64); a1 += __shfl_xor(a1, 16, 64);
    a2 += __shfl_xor(a2, 16, 64); a3 += __shfl_xor(a3, 16, 64);
    if (sub == 0)
        ((float4*)xacc)[node * 8 + f] = make_float4(a0, a1, a2, a3);
}

// ---------------- gather pass B: src>=HALF edges + self + bias + relu ----------------
__global__ __launch_bounds__(256) void gatherB_kernel(
    const int* __restrict__ rowptrB, const int* __restrict__ degpack,
    const int* __restrict__ csr_src, const uint* __restrict__ tb,
    const float* __restrict__ dinv, const float* __restrict__ xacc,
    const float* __restrict__ bias, float* __restrict__ xo, int n) {
    int tid = blockIdx.x * blockDim.x + threadIdx.x;
    int node = tid >> 5;
    if (node >= n) return;
    int lane = tid & 31;
    int sub = lane >> 3, f = lane & 7;
    int beg = rowptrB[node];
    int end = beg + (degpack[node] >> 16);
    float a0 = 0.f, a1 = 0.f, a2 = 0.f, a3 = 0.f;
    gath_range(beg, end, sub, f, csr_src, tb, a0, a1, a2, a3);
    a0 += __shfl_xor(a0, 8, 64);  a1 += __shfl_xor(a1, 8, 64);
    a2 += __shfl_xor(a2, 8, 64);  a3 += __shfl_xor(a3, 8, 64);
    a0 += __shfl_xor(a0, 16, 64); a1 += __shfl_xor(a1, 16, 64);
    a2 += __shfl_xor(a2, 16, 64); a3 += __shfl_xor(a3, 16, 64);
    if (sub == 0) {
        float dd = dinv[node];
        float4 pa = ((const float4*)xacc)[node * 8 + f];
        uint2 sv = *(const uint2*)&tb[node * 16 + f * 2];   // tbs = t*dinv
        a0 += pa.x + bf16lo(sv.x); a1 += pa.y + bf16hi(sv.x);
        a2 += pa.z + bf16lo(sv.y); a3 += pa.w + bf16hi(sv.y);
        float4 bb = *(const float4*)&bias[f * 4];
        float4 r;
        r.x = fmaxf(a0 * dd + bb.x, 0.f);
        r.y = fmaxf(a1 * dd + bb.y, 0.f);
        r.z = fmaxf(a2 * dd + bb.z, 0.f);
        r.w = fmaxf(a3 * dd + bb.w, 0.f);
        ((float4*)xo)[node * 8 + f] = r;
    }
}

// ---------------- h64 = relu(concat(x1,x2,x3) @ fc1_w + fc1_b) ----------------
__global__ __launch_bounds__(256) void fc1_tiled_kernel(
    const float* __restrict__ x1, const float* __restrict__ x2, const float* __restrict__ x3,
    const float* __restrict__ W, const float* __restrict__ b, float* __restrict__ h64, int n) {
    __shared__ float Wl[96 * 64];   // 24 KB
    __shared__ float Xl[64][100];   // 25.6 KB
    int t = threadIdx.x;
    for (int i = t; i < 96 * 64; i += 256) Wl[i] = W[i];
    int tile0 = blockIdx.x * 64;
    for (int idx = t; idx < 64 * 32; idx += 256) {
        int r = idx >> 5, j = idx & 31;
        int node = tile0 + r;
        float v1 = 0.f, v2 = 0.f, v3 = 0.f;
        if (node < n) {
            v1 = x1[node * 32 + j];
            v2 = x2[node * 32 + j];
            v3 = x3[node * 32 + j];
        }
        Xl[r][j] = v1; Xl[r][32 + j] = v2; Xl[r][64 + j] = v3;
    }
    __syncthreads();
    int cg = t & 15, ng = t >> 4;
    int c0 = cg * 4;
    float4 bb = *(const float4*)&b[c0];
    float acc[4][4];
#pragma unroll
    for (int i = 0; i < 4; i++) {
        acc[i][0] = bb.x; acc[i][1] = bb.y; acc[i][2] = bb.z; acc[i][3] = bb.w;
    }
#pragma unroll 4
    for (int k4 = 0; k4 < 24; k4++) {
        float4 w0 = *(const float4*)&Wl[(k4 * 4 + 0) * 64 + c0];
        float4 w1 = *(const float4*)&Wl[(k4 * 4 + 1) * 64 + c0];
        float4 w2 = *(const float4*)&Wl[(k4 * 4 + 2) * 64 + c0];
        float4 w3 = *(const float4*)&Wl[(k4 * 4 + 3) * 64 + c0];
#pragma unroll
        for (int i = 0; i < 4; i++) {
            float4 xv = *(const float4*)&Xl[ng * 4 + i][k4 * 4];
            acc[i][0] += xv.x * w0.x + xv.y * w1.x + xv.z * w2.x + xv.w * w3.x;
            acc[i][1] += xv.x * w0.y + xv.y * w1.y + xv.z * w2.y + xv.w * w3.y;
            acc[i][2] += xv.x * w0.z + xv.y * w1.z + xv.z * w2.z + xv.w * w3.z;
            acc[i][3] += xv.x * w0.w + xv.y * w1.w + xv.z * w2.w + xv.w * w3.w;
        }
    }
#pragma unroll
    for (int i = 0; i < 4; i++) {
        int node = tile0 + ng * 4 + i;
        if (node < n)
            *(float4*)&h64[node * 64 + c0] =
                make_float4(fmaxf(acc[i][0], 0.f), fmaxf(acc[i][1], 0.f),
                            fmaxf(acc[i][2], 0.f), fmaxf(acc[i][3], 0.f));
    }
}

// ---------------- h128 = relu(h64 @ fc2a_w + b) + pooling via LDS spool ----------------
__global__ __launch_bounds__(256) void fc2a_pool_kernel(
    const float* __restrict__ h64, const float* __restrict__ W, const float* __restrict__ b,
    const int* __restrict__ batch, float* __restrict__ pooled, int n) {
    __shared__ float Al[64 * 64];    // 16 KB
    __shared__ float spool[8][128];  // 4 KB
    __shared__ int batchl[64];
    int t = threadIdx.x;
    for (int i = t; i < 8 * 128; i += 256) ((float*)spool)[i] = 0.f;
    int tile0 = blockIdx.x * 64;
    for (int idx = t; idx < 64 * 16; idx += 256) {
        int r = idx >> 4, q = idx & 15;
        int node = tile0 + r;
        float4 v = (node < n) ? *(const float4*)&h64[(size_t)node * 64 + q * 4]
                              : make_float4(0.f, 0.f, 0.f, 0.f);
        *(float4*)&Al[r * 64 + q * 4] = v;
    }
    if (t < 64) batchl[t] = (tile0 + t < n) ? batch[tile0 + t] : -1;
    __syncthreads();
    int cg = t & 31, ng = t >> 5;
    int c0 = cg * 4;
    int base = ng * 8;
    float acc[8][4];
#pragma unroll
    for (int i = 0; i < 8; i++)
        for (int j = 0; j < 4; j++) acc[i][j] = 0.f;
#pragma unroll 4
    for (int k4 = 0; k4 < 16; k4++) {
        float4 w0 = *(const float4*)&W[(k4 * 4 + 0) * 128 + c0];
        float4 w1 = *(const float4*)&W[(k4 * 4 + 1) * 128 + c0];
        float4 w2 = *(const float4*)&W[(k4 * 4 + 2) * 128 + c0];
        float4 w3 = *(const float4*)&W[(k4 * 4 + 3) * 128 + c0];
#pragma unroll
        for (int i = 0; i < 8; i++) {
            float4 hv = *(const float4*)&Al[(base + i) * 64 + k4 * 4];
            acc[i][0] += hv.x * w0.x + hv.y * w1.x + hv.z * w2.x + hv.w * w3.x;
            acc[i][1] += hv.x * w0.y + hv.y * w1.y + hv.z * w2.y + hv.w * w3.y;
            acc[i][2] += hv.x * w0.z + hv.y * w1.z + hv.z * w2.z + hv.w * w3.z;
            acc[i][3] += hv.x * w0.w + hv.y * w1.w + hv.z * w2.w + hv.w * w3.w;
        }
    }
    float4 bb = *(const float4*)&b[c0];
    int g0 = batchl[0];
    if (tile0 + base < n) {
        float r0 = 0.f, r1 = 0.f, r2 = 0.f, r3 = 0.f;
        int curg = batchl[base];
        for (int i = 0; i < 8; i++) {
            int node = tile0 + base + i;
            if (node >= n) break;
            int gi = batchl[base + i];
            if (gi != curg) {
                int sg = curg - g0;
                if (sg < 8) {
                    atomicAdd(&spool[sg][c0 + 0], r0); atomicAdd(&spool[sg][c0 + 1], r1);
                    atomicAdd(&spool[sg][c0 + 2], r2); atomicAdd(&spool[sg][c0 + 3], r3);
                } else {
                    float* dst = pooled + (long long)curg * 128 + c0;
                    atomicAdd(dst + 0, r0); atomicAdd(dst + 1, r1);
                    atomicAdd(dst + 2, r2); atomicAdd(dst + 3, r3);
                }
                r0 = r1 = r2 = r3 = 0.f;
                curg = gi;
            }
            r0 += fmaxf(acc[i][0] + bb.x, 0.f);
            r1 += fmaxf(acc[i][1] + bb.y, 0.f);
            r2 += fmaxf(acc[i][2] + bb.z, 0.f);
            r3 += fmaxf(acc[i][3] + bb.w, 0.f);
        }
        int sg = curg - g0;
        if (sg < 8) {
            atomicAdd(&spool[sg][c0 + 0], r0); atomicAdd(&spool[sg][c0 + 1], r1);
            atomicAdd(&spool[sg][c0 + 2], r2); atomicAdd(&spool[sg][c0 + 3], r3);
        } else {
            float* dst = pooled + (long long)curg * 128 + c0;
            atomicAdd(dst + 0, r0); atomicAdd(dst + 1, r1);
            atomicAdd(dst + 2, r2); atomicAdd(dst + 3, r3);
        }
    }
    __syncthreads();
    int nvalid = min(n - tile0, 64);
    int gmax = batchl[nvalid - 1];
    for (int i = t; i < 8 * 128; i += 256) {
        int sg = i >> 7, c = i & 127;
        int g = g0 + sg;
        if (g <= gmax) {
            float v = spool[sg][c];
            if (v != 0.f) atomicAdd(&pooled[(long long)g * 128 + c], v);
        }
    }
}

// ---------------- classifier: one wave per graph ----------------
__global__ __launch_bounds__(64) void head_kernel(
    const float* __restrict__ pooled, const float* __restrict__ W2b,
    const float* __restrict__ b2b, const float* __restrict__ W3,
    const float* __restrict__ b3, float* __restrict__ out) {
    int g = blockIdx.x;
    int k = threadIdx.x;
    const float* p0 = pooled + (long long)g * 128;
    float acc = b2b[k];
    for (int j = 0; j < 128; j += 4) {
        float4 pv = *(const float4*)&p0[j];
        acc += pv.x * W2b[j * 64 + k] + pv.y * W2b[(j + 1) * 64 + k] +
               pv.z * W2b[(j + 2) * 64 + k] + pv.w * W2b[(j + 3) * 64 + k];
    }
    float h = fmaxf(acc, 0.f);
    float2 w3 = *(const float2*)&W3[k * 2];
    float l0 = h * w3.x;
    float l1 = h * w3.y;
#pragma unroll
    for (int off = 1; off < 64; off <<= 1) {
        l0 += __shfl_xor(l0, off, 64);
        l1 += __shfl_xor(l1, off, 64);
    }
    if (k == 0) {
        l0 += b3[0];
        l1 += b3[1];
        float m = fmaxf(l0, l1);
        float lse = m + logf(expf(l0 - m) + expf(l1 - m));
        out[g * 2 + 0] = l0 - lse;
        out[g * 2 + 1] = l1 - lse;
    }
}

extern "C" void kernel_launch(void* const* d_in, const int* in_sizes, int n_in,
                              void* d_out, int out_size, void* d_ws, size_t ws_size,
                              hipStream_t stream) {
    const float* x     = (const float*)d_in[0];
    const int*   ei    = (const int*)d_in[1];
    const int*   srcI  = ei;
    const int*   dstI  = ei + NE;
    const int*   batch = (const int*)d_in[2];
    const float* W1    = (const float*)d_in[3];
    const float* b1    = (const float*)d_in[4];
    const float* W2    = (const float*)d_in[5];
    const float* b2    = (const float*)d_in[6];
    const float* W3w   = (const float*)d_in[7];
    const float* b3w   = (const float*)d_in[8];
    const float* fc1w  = (const float*)d_in[9];
    const float* fc1b  = (const float*)d_in[10];
    const float* fc2aw = (const float*)d_in[11];
    const float* fc2ab = (const float*)d_in[12];
    const float* fc2bw = (const float*)d_in[13];
    const float* fc2bb = (const float*)d_in[14];
    const float* fc3w  = (const float*)d_in[15];
    const float* fc3b  = (const float*)d_in[16];
    float* out = (float*)d_out;

    // ---- workspace layout ----
    char* p = (char*)d_ws;
    int* pcur = (int*)p;                  p += 2048;
    int* rowptrA = (int*)p;               p += (size_t)(NN + 4) * 4;
    int* rowptrB = (int*)p;               p += (size_t)(NN + 4) * 4;
    int* degpack = (int*)p;               p += (size_t)NN * 4;
    float* dinv = (float*)p;              p += (size_t)NN * 4;
    int* temp = (int*)p;                  p += (size_t)NPART * CAP * 4;  // 16.0 MB
    int* csr_src = (int*)p;               p += (size_t)NPART * CAP * 4;  // 16.0 MB
    uint* tb = (uint*)p;                  p += (size_t)NN * 16 * 4;      // 6.4 MB bf16
    float* xacc = (float*)p;              p += (size_t)NN * 32 * 4;      // 12.8 MB
    float* x1 = (float*)p;                p += (size_t)NN * 32 * 4;
    float* x2 = (float*)p;                p += (size_t)NN * 32 * 4;
    float* x3 = (float*)p;                p += (size_t)NN * 32 * 4;
    float* pooled = (float*)p;            p += (size_t)NG * 128 * 4;
    float* h64 = (float*)temp;            // alias: temp+csr dead after layer-3 gather

    const int thr = 256;
    int gTile64 = (NN + 63) / 64;
    int gTile128 = (NN + 127) / 128;
    int gGather = (NN * 32 + thr - 1) / thr;
    int gEdge = (NE + CHUNK - 1) / CHUNK;

    // ---- CSR build ----
    zero_misc_kernel<<<(NG * 128 + thr - 1) / thr, thr, 0, stream>>>(pcur, pooled);
    part1_kernel<<<gEdge, thr, 0, stream>>>(srcI, dstI, pcur, temp, NE);
    part2_kernel<<<NPART, thr, 0, stream>>>(temp, pcur, rowptrA, rowptrB, degpack,
                                            dinv, csr_src, NN);

    // ---- conv layers: prescaled bf16 transform -> two L2-resident gather passes ----
    gemm128_32_direct<<<gTile128, thr, 0, stream>>>(x, W1, dinv, tb, NN);
    gatherA_kernel<<<gGather, thr, 0, stream>>>(rowptrA, degpack, csr_src, tb, xacc, NN);
    gatherB_kernel<<<gGather, thr, 0, stream>>>(rowptrB, degpack, csr_src, tb, dinv, xacc, b1, x1, NN);

    gemm32_32_kernel<<<gTile128, thr, 0, stream>>>(x1, W2, dinv, tb, NN);
    gatherA_kernel<<<gGather, thr, 0, stream>>>(rowptrA, degpack, csr_src, tb, xacc, NN);
    gatherB_kernel<<<gGather, thr, 0, stream>>>(rowptrB, degpack, csr_src, tb, dinv, xacc, b2, x2, NN);

    gemm32_32_kernel<<<gTile128, thr, 0, stream>>>(x2, W3w, dinv, tb, NN);
    gatherA_kernel<<<gGather, thr, 0, stream>>>(rowptrA, degpack, csr_src, tb, xacc, NN);
    gatherB_kernel<<<gGather, thr, 0, stream>>>(rowptrB, degpack, csr_src, tb, dinv, xacc, b3w, x3, NN);

    // ---- MLP head ----
    fc1_tiled_kernel<<<gTile64, thr, 0, stream>>>(x1, x2, x3, fc1w, fc1b, h64, NN);
    fc2a_pool_kernel<<<gTile64, thr, 0, stream>>>(h64, fc2aw, fc2ab, batch, pooled, NN);

    // ---- classifier ----
    head_kernel<<<NG, 64, 0, stream>>>(pooled, fc2bw, fc2bb, fc3w, fc3b, out);
    (void)ws_size; (void)in_sizes; (void)n_in; (void)out_size;
}

// Round 18
// 357.657 us; speedup vs baseline: 1.0724x; 1.0724x over previous
//
#include <hip/hip_runtime.h>
#include <math.h>

#define NN 100000
#define NE 3200000
#define NG 512
#define PSHIFT 8
#define NPART ((NN + 255) >> 8)   // 391 partitions of 256 dst nodes
#define CHUNK 4096                // edges per binning block
#define CAP 10240                 // fixed per-partition window (max expected ~8.5K)

typedef unsigned int uint;

__device__ inline uint bf16rne(float f) {
    uint u = __float_as_uint(f);
    return (u + 0x7fffu + ((u >> 16) & 1u)) >> 16;
}
__device__ inline float bf16lo(uint v) { return __uint_as_float(v << 16); }
__device__ inline float bf16hi(uint v) { return __uint_as_float(v & 0xffff0000u); }

// ---------------- init pcur (partition window bases) + pooled ----------------
__global__ void zero_misc_kernel(int* pcur, float* pooled) {
    int i = blockIdx.x * blockDim.x + threadIdx.x;
    if (i < NPART) pcur[i] = i * CAP;
    if (i < NG * 128) pooled[i] = 0.f;
}

// ---------------- part1: LDS-binned partition scatter into fixed-CAP windows ----------------
__global__ __launch_bounds__(256) void part1_kernel(
    const int* __restrict__ src, const int* __restrict__ dst,
    int* pcur, int* __restrict__ temp, int e) {
    __shared__ int cnt[NPART];
    __shared__ int gbase[NPART];
    int t = threadIdx.x;
    for (int i = t; i < NPART; i += 256) cnt[i] = 0;
    __syncthreads();
    int base = blockIdx.x * CHUNK;
    int pv[16], pp[16], rr[16];
#pragma unroll
    for (int j = 0; j < 16; j++) {
        int i = base + j * 256 + t;
        if (i < e) {
            int s = src[i], d = dst[i];
            pp[j] = d >> PSHIFT;
            pv[j] = (s << PSHIFT) | (d & 255);
            rr[j] = atomicAdd(&cnt[pp[j]], 1);
        } else {
            pp[j] = -1; pv[j] = 0; rr[j] = 0;
        }
    }
    __syncthreads();
    for (int i = t; i < NPART; i += 256)
        gbase[i] = cnt[i] ? atomicAdd(&pcur[i], cnt[i]) : 0;
    __syncthreads();
#pragma unroll
    for (int j = 0; j < 16; j++)
        if (pp[j] >= 0) temp[gbase[pp[j]] + rr[j]] = pv[j];
}

// ---------------- part2: per-partition degree count + local scan + scatter ----------------
__global__ __launch_bounds__(256) void part2_kernel(
    const int* __restrict__ temp, const int* __restrict__ pcur,
    int* __restrict__ rowptr, int* __restrict__ deg,
    float* __restrict__ dinv, int* __restrict__ csr_src, int n) {
    __shared__ int cnt[256], sc[256];
    int p = blockIdx.x;
    int d0 = p << PSHIFT;
    int t = threadIdx.x;
    cnt[t] = 0;
    __syncthreads();
    int lo = p * CAP, hi = pcur[p];
    for (int i = lo + t; i < hi; i += 256) atomicAdd(&cnt[temp[i] & 255], 1);
    __syncthreads();
    int myc = cnt[t];
    sc[t] = myc;
    __syncthreads();
    for (int off = 1; off < 256; off <<= 1) {
        int v = (t >= off) ? sc[t - off] : 0;
        __syncthreads();
        sc[t] += v;
        __syncthreads();
    }
    int ex = (t > 0) ? sc[t - 1] : 0;
    int b = lo + ex;
    int d = d0 + t;
    if (d < n) {
        rowptr[d] = b;
        deg[d] = myc;
        dinv[d] = rsqrtf((float)(myc + 1));
    }
    __syncthreads();
    cnt[t] = 0;   // reuse as cursor
    sc[t] = b;    // stable base in LDS
    __syncthreads();
    for (int i = lo + t; i < hi; i += 256) {
        int v = temp[i];
        int ld = v & 255;
        int slot = sc[ld] + atomicAdd(&cnt[ld], 1);
        csr_src[slot] = v >> PSHIFT;
    }
}

// ---------------- tbs[n,32] (bf16) = (x[n,128] @ W[128,32]) * dinv[n] ----------------
__global__ __launch_bounds__(256) void gemm128_32_direct(
    const float* __restrict__ x, const float* __restrict__ W,
    const float* __restrict__ dinv, uint* __restrict__ tb, int n) {
    __shared__ float Wl[128 * 32];   // 16 KB only
    int t = threadIdx.x;
    for (int i = t; i < 128 * 32; i += 256) Wl[i] = W[i];
    __syncthreads();
    int tile0 = blockIdx.x * 128;
    int cg = t & 7, ng = t >> 3;
    int c0 = cg * 4;
    const float* xp[4];
    int nodev[4];
#pragma unroll
    for (int i = 0; i < 4; i++) {
        nodev[i] = tile0 + ng + 32 * i;
        xp[i] = x + (size_t)min(nodev[i], n - 1) * 128;
    }
    float acc[4][4];
#pragma unroll
    for (int i = 0; i < 4; i++)
        for (int j = 0; j < 4; j++) acc[i][j] = 0.f;
#pragma unroll 2
    for (int k4 = 0; k4 < 32; k4++) {
        float4 w0 = *(const float4*)&Wl[(k4 * 4 + 0) * 32 + c0];
        float4 w1 = *(const float4*)&Wl[(k4 * 4 + 1) * 32 + c0];
        float4 w2 = *(const float4*)&Wl[(k4 * 4 + 2) * 32 + c0];
        float4 w3 = *(const float4*)&Wl[(k4 * 4 + 3) * 32 + c0];
#pragma unroll
        for (int i = 0; i < 4; i++) {
            float4 xv = *(const float4*)&xp[i][k4 * 4];
            acc[i][0] += xv.x * w0.x + xv.y * w1.x + xv.z * w2.x + xv.w * w3.x;
            acc[i][1] += xv.x * w0.y + xv.y * w1.y + xv.z * w2.y + xv.w * w3.y;
            acc[i][2] += xv.x * w0.z + xv.y * w1.z + xv.z * w2.z + xv.w * w3.z;
            acc[i][3] += xv.x * w0.w + xv.y * w1.w + xv.z * w2.w + xv.w * w3.w;
        }
    }
#pragma unroll
    for (int i = 0; i < 4; i++) {
        if (nodev[i] < n) {
            float ds = dinv[nodev[i]];
            uint2 pk;
            pk.x = bf16rne(acc[i][0] * ds) | (bf16rne(acc[i][1] * ds) << 16);
            pk.y = bf16rne(acc[i][2] * ds) | (bf16rne(acc[i][3] * ds) << 16);
            *(uint2*)&tb[nodev[i] * 16 + cg * 2] = pk;
        }
    }
}

// ---------------- tbs[n,32] (bf16) = (xin[n,32] @ W[32,32]) * dinv[n] ----------------
__global__ __launch_bounds__(256) void gemm32_32_kernel(
    const float* __restrict__ xin, const float* __restrict__ W,
    const float* __restrict__ dinv, uint* __restrict__ tb, int n) {
    __shared__ float Wl[32 * 32];    // 4 KB
    __shared__ float Xl[128][36];    // 18.4 KB (32 k + pad 4)
    int t = threadIdx.x;
    for (int i = t; i < 32 * 32; i += 256) Wl[i] = W[i];
    int tile0 = blockIdx.x * 128;
    for (int idx = t; idx < 128 * 8; idx += 256) {
        int r = idx >> 3, q = idx & 7;
        int node = tile0 + r;
        float4 v = (node < n) ? *(const float4*)&xin[(size_t)node * 32 + q * 4]
                              : make_float4(0.f, 0.f, 0.f, 0.f);
        *(float4*)&Xl[r][q * 4] = v;
    }
    __syncthreads();
    int cg = t & 7, ng = t >> 3;
    int c0 = cg * 4;
    float acc[4][4];
#pragma unroll
    for (int i = 0; i < 4; i++)
        for (int j = 0; j < 4; j++) acc[i][j] = 0.f;
#pragma unroll
    for (int k4 = 0; k4 < 8; k4++) {
        float4 w0 = *(const float4*)&Wl[(k4 * 4 + 0) * 32 + c0];
        float4 w1 = *(const float4*)&Wl[(k4 * 4 + 1) * 32 + c0];
        float4 w2 = *(const float4*)&Wl[(k4 * 4 + 2) * 32 + c0];
        float4 w3 = *(const float4*)&Wl[(k4 * 4 + 3) * 32 + c0];
#pragma unroll
        for (int i = 0; i < 4; i++) {
            float4 xv = *(const float4*)&Xl[ng + 32 * i][k4 * 4];
            acc[i][0] += xv.x * w0.x + xv.y * w1.x + xv.z * w2.x + xv.w * w3.x;
            acc[i][1] += xv.x * w0.y + xv.y * w1.y + xv.z * w2.y + xv.w * w3.y;
            acc[i][2] += xv.x * w0.z + xv.y * w1.z + xv.z * w2.z + xv.w * w3.z;
            acc[i][3] += xv.x * w0.w + xv.y * w1.w + xv.z * w2.w + xv.w * w3.w;
        }
    }
#pragma unroll
    for (int i = 0; i < 4; i++) {
        int node = tile0 + ng + 32 * i;
        if (node < n) {
            float ds = dinv[node];
            uint2 pk;
            pk.x = bf16rne(acc[i][0] * ds) | (bf16rne(acc[i][1] * ds) << 16);
            pk.y = bf16rne(acc[i][2] * ds) | (bf16rne(acc[i][3] * ds) << 16);
            *(uint2*)&tb[node * 16 + cg * 2] = pk;
        }
    }
}

// ---------------- fused gather: single range, prescaled tb, 8/4-deep tiers ----------------
__global__ __launch_bounds__(256) void gather_kernel(
    const int* __restrict__ rowptr, const int* __restrict__ deg,
    const int* __restrict__ csr_src, const uint* __restrict__ tb,
    const float* __restrict__ dinv, const float* __restrict__ bias,
    float* __restrict__ xo, int n) {
    int tid = blockIdx.x * blockDim.x + threadIdx.x;
    int node = tid >> 5;
    if (node >= n) return;
    int lane = tid & 31;
    int sub = lane >> 3, f = lane & 7;    // 4 edge-slots x 8 feature-lanes (uint2 each)
    int beg = rowptr[node];
    int end = beg + deg[node];
    float a0 = 0.f, a1 = 0.f, a2 = 0.f, a3 = 0.f;
    int e = beg + sub;
    // tier 1: 8-deep
    for (; e + 28 < end; e += 32) {
        int s0 = csr_src[e],      s1 = csr_src[e + 4],  s2 = csr_src[e + 8],  s3 = csr_src[e + 12];
        int s4 = csr_src[e + 16], s5 = csr_src[e + 20], s6 = csr_src[e + 24], s7 = csr_src[e + 28];
        uint2 v0 = *(const uint2*)&tb[s0 * 16 + f * 2];
        uint2 v1 = *(const uint2*)&tb[s1 * 16 + f * 2];
        uint2 v2 = *(const uint2*)&tb[s2 * 16 + f * 2];
        uint2 v3 = *(const uint2*)&tb[s3 * 16 + f * 2];
        uint2 v4 = *(const uint2*)&tb[s4 * 16 + f * 2];
        uint2 v5 = *(const uint2*)&tb[s5 * 16 + f * 2];
        uint2 v6 = *(const uint2*)&tb[s6 * 16 + f * 2];
        uint2 v7 = *(const uint2*)&tb[s7 * 16 + f * 2];
        a0 += bf16lo(v0.x) + bf16lo(v1.x) + bf16lo(v2.x) + bf16lo(v3.x)
            + bf16lo(v4.x) + bf16lo(v5.x) + bf16lo(v6.x) + bf16lo(v7.x);
        a1 += bf16hi(v0.x) + bf16hi(v1.x) + bf16hi(v2.x) + bf16hi(v3.x)
            + bf16hi(v4.x) + bf16hi(v5.x) + bf16hi(v6.x) + bf16hi(v7.x);
        a2 += bf16lo(v0.y) + bf16lo(v1.y) + bf16lo(v2.y) + bf16lo(v3.y)
            + bf16lo(v4.y) + bf16lo(v5.y) + bf16lo(v6.y) + bf16lo(v7.y);
        a3 += bf16hi(v0.y) + bf16hi(v1.y) + bf16hi(v2.y) + bf16hi(v3.y)
            + bf16hi(v4.y) + bf16hi(v5.y) + bf16hi(v6.y) + bf16hi(v7.y);
    }
    // tier 2: 4-deep
    for (; e + 12 < end; e += 16) {
        int s0 = csr_src[e], s1 = csr_src[e + 4], s2 = csr_src[e + 8], s3 = csr_src[e + 12];
        uint2 v0 = *(const uint2*)&tb[s0 * 16 + f * 2];
        uint2 v1 = *(const uint2*)&tb[s1 * 16 + f * 2];
        uint2 v2 = *(const uint2*)&tb[s2 * 16 + f * 2];
        uint2 v3 = *(const uint2*)&tb[s3 * 16 + f * 2];
        a0 += bf16lo(v0.x) + bf16lo(v1.x) + bf16lo(v2.x) + bf16lo(v3.x);
        a1 += bf16hi(v0.x) + bf16hi(v1.x) + bf16hi(v2.x) + bf16hi(v3.x);
        a2 += bf16lo(v0.y) + bf16lo(v1.y) + bf16lo(v2.y) + bf16lo(v3.y);
        a3 += bf16hi(v0.y) + bf16hi(v1.y) + bf16hi(v2.y) + bf16hi(v3.y);
    }
    // tail
    for (; e < end; e += 4) {
        int s = csr_src[e];
        uint2 v = *(const uint2*)&tb[s * 16 + f * 2];
        a0 += bf16lo(v.x); a1 += bf16hi(v.x);
        a2 += bf16lo(v.y); a3 += bf16hi(v.y);
    }
    a0 += __shfl_xor(a0, 8, 64);  a1 += __shfl_xor(a1, 8, 64);
    a2 += __shfl_xor(a2, 8, 64);  a3 += __shfl_xor(a3, 8, 64);
    a0 += __shfl_xor(a0, 16, 64); a1 += __shfl_xor(a1, 16, 64);
    a2 += __shfl_xor(a2, 16, 64); a3 += __shfl_xor(a3, 16, 64);
    if (sub == 0) {
        float dd = dinv[node];
        uint2 sv = *(const uint2*)&tb[node * 16 + f * 2];   // tbs = t*dinv
        a0 += bf16lo(sv.x); a1 += bf16hi(sv.x);
        a2 += bf16lo(sv.y); a3 += bf16hi(sv.y);
        float4 bb = *(const float4*)&bias[f * 4];
        float4 r;
        r.x = fmaxf(a0 * dd + bb.x, 0.f);
        r.y = fmaxf(a1 * dd + bb.y, 0.f);
        r.z = fmaxf(a2 * dd + bb.z, 0.f);
        r.w = fmaxf(a3 * dd + bb.w, 0.f);
        ((float4*)xo)[node * 8 + f] = r;
    }
}

// ---------------- h64 = relu(concat(x1,x2,x3) @ fc1_w + fc1_b), float4 LDS reads ----------------
__global__ __launch_bounds__(256) void fc1_tiled_kernel(
    const float* __restrict__ x1, const float* __restrict__ x2, const float* __restrict__ x3,
    const float* __restrict__ W, const float* __restrict__ b, float* __restrict__ h64, int n) {
    __shared__ float Wl[96 * 64];   // 24 KB
    __shared__ float Xl[64][100];   // 25.6 KB
    int t = threadIdx.x;
    for (int i = t; i < 96 * 64; i += 256) Wl[i] = W[i];
    int tile0 = blockIdx.x * 64;
    for (int idx = t; idx < 64 * 32; idx += 256) {
        int r = idx >> 5, j = idx & 31;
        int node = tile0 + r;
        float v1 = 0.f, v2 = 0.f, v3 = 0.f;
        if (node < n) {
            v1 = x1[node * 32 + j];
            v2 = x2[node * 32 + j];
            v3 = x3[node * 32 + j];
        }
        Xl[r][j] = v1; Xl[r][32 + j] = v2; Xl[r][64 + j] = v3;
    }
    __syncthreads();
    int cg = t & 15, ng = t >> 4;
    int c0 = cg * 4;
    float4 bb = *(const float4*)&b[c0];
    float acc[4][4];
#pragma unroll
    for (int i = 0; i < 4; i++) {
        acc[i][0] = bb.x; acc[i][1] = bb.y; acc[i][2] = bb.z; acc[i][3] = bb.w;
    }
#pragma unroll 4
    for (int k4 = 0; k4 < 24; k4++) {
        float4 w0 = *(const float4*)&Wl[(k4 * 4 + 0) * 64 + c0];
        float4 w1 = *(const float4*)&Wl[(k4 * 4 + 1) * 64 + c0];
        float4 w2 = *(const float4*)&Wl[(k4 * 4 + 2) * 64 + c0];
        float4 w3 = *(const float4*)&Wl[(k4 * 4 + 3) * 64 + c0];
#pragma unroll
        for (int i = 0; i < 4; i++) {
            float4 xv = *(const float4*)&Xl[ng * 4 + i][k4 * 4];
            acc[i][0] += xv.x * w0.x + xv.y * w1.x + xv.z * w2.x + xv.w * w3.x;
            acc[i][1] += xv.x * w0.y + xv.y * w1.y + xv.z * w2.y + xv.w * w3.y;
            acc[i][2] += xv.x * w0.z + xv.y * w1.z + xv.z * w2.z + xv.w * w3.z;
            acc[i][3] += xv.x * w0.w + xv.y * w1.w + xv.z * w2.w + xv.w * w3.w;
        }
    }
#pragma unroll
    for (int i = 0; i < 4; i++) {
        int node = tile0 + ng * 4 + i;
        if (node < n)
            *(float4*)&h64[node * 64 + c0] =
                make_float4(fmaxf(acc[i][0], 0.f), fmaxf(acc[i][1], 0.f),
                            fmaxf(acc[i][2], 0.f), fmaxf(acc[i][3], 0.f));
    }
}

// ---------------- h128 = relu(h64 @ fc2a_w + b) + pooling via LDS spool ----------------
// R14 variant: Wl and Al both LDS-staged, float4 reads everywhere (best measured: 45.2 us).
__global__ __launch_bounds__(256) void fc2a_pool_kernel(
    const float* __restrict__ h64, const float* __restrict__ W, const float* __restrict__ b,
    const int* __restrict__ batch, float* __restrict__ pooled, int n) {
    __shared__ float Wl[64 * 128];   // 32 KB
    __shared__ float Al[64 * 64];    // 16 KB
    __shared__ float spool[8][128];  // 4 KB
    __shared__ int batchl[64];
    int t = threadIdx.x;
    for (int i = t; i < 64 * 128; i += 256) Wl[i] = W[i];
    for (int i = t; i < 8 * 128; i += 256) ((float*)spool)[i] = 0.f;
    int tile0 = blockIdx.x * 64;
    for (int idx = t; idx < 64 * 16; idx += 256) {
        int r = idx >> 4, q = idx & 15;
        int node = tile0 + r;
        float4 v = (node < n) ? *(const float4*)&h64[(size_t)node * 64 + q * 4]
                              : make_float4(0.f, 0.f, 0.f, 0.f);
        *(float4*)&Al[r * 64 + q * 4] = v;
    }
    if (t < 64) batchl[t] = (tile0 + t < n) ? batch[tile0 + t] : -1;
    __syncthreads();
    int cg = t & 31, ng = t >> 5;
    int c0 = cg * 4;
    int base = ng * 8;
    float acc[8][4];
#pragma unroll
    for (int i = 0; i < 8; i++)
        for (int j = 0; j < 4; j++) acc[i][j] = 0.f;
#pragma unroll 4
    for (int k4 = 0; k4 < 16; k4++) {
        float4 w0 = *(const float4*)&Wl[(k4 * 4 + 0) * 128 + c0];
        float4 w1 = *(const float4*)&Wl[(k4 * 4 + 1) * 128 + c0];
        float4 w2 = *(const float4*)&Wl[(k4 * 4 + 2) * 128 + c0];
        float4 w3 = *(const float4*)&Wl[(k4 * 4 + 3) * 128 + c0];
#pragma unroll
        for (int i = 0; i < 8; i++) {
            float4 hv = *(const float4*)&Al[(base + i) * 64 + k4 * 4];
            acc[i][0] += hv.x * w0.x + hv.y * w1.x + hv.z * w2.x + hv.w * w3.x;
            acc[i][1] += hv.x * w0.y + hv.y * w1.y + hv.z * w2.y + hv.w * w3.y;
            acc[i][2] += hv.x * w0.z + hv.y * w1.z + hv.z * w2.z + hv.w * w3.z;
            acc[i][3] += hv.x * w0.w + hv.y * w1.w + hv.z * w2.w + hv.w * w3.w;
        }
    }
    float4 bb = *(const float4*)&b[c0];
    int g0 = batchl[0];
    if (tile0 + base < n) {
        float r0 = 0.f, r1 = 0.f, r2 = 0.f, r3 = 0.f;
        int curg = batchl[base];
        for (int i = 0; i < 8; i++) {
            int node = tile0 + base + i;
            if (node >= n) break;
            int gi = batchl[base + i];
            if (gi != curg) {
                int sg = curg - g0;
                if (sg < 8) {
                    atomicAdd(&spool[sg][c0 + 0], r0); atomicAdd(&spool[sg][c0 + 1], r1);
                    atomicAdd(&spool[sg][c0 + 2], r2); atomicAdd(&spool[sg][c0 + 3], r3);
                } else {
                    float* dst = pooled + (long long)curg * 128 + c0;
                    atomicAdd(dst + 0, r0); atomicAdd(dst + 1, r1);
                    atomicAdd(dst + 2, r2); atomicAdd(dst + 3, r3);
                }
                r0 = r1 = r2 = r3 = 0.f;
                curg = gi;
            }
            r0 += fmaxf(acc[i][0] + bb.x, 0.f);
            r1 += fmaxf(acc[i][1] + bb.y, 0.f);
            r2 += fmaxf(acc[i][2] + bb.z, 0.f);
            r3 += fmaxf(acc[i][3] + bb.w, 0.f);
        }
        int sg = curg - g0;
        if (sg < 8) {
            atomicAdd(&spool[sg][c0 + 0], r0); atomicAdd(&spool[sg][c0 + 1], r1);
            atomicAdd(&spool[sg][c0 + 2], r2); atomicAdd(&spool[sg][c0 + 3], r3);
        } else {
            float* dst = pooled + (long long)curg * 128 + c0;
            atomicAdd(dst + 0, r0); atomicAdd(dst + 1, r1);
            atomicAdd(dst + 2, r2); atomicAdd(dst + 3, r3);
        }
    }
    __syncthreads();
    int nvalid = min(n - tile0, 64);
    int gmax = batchl[nvalid - 1];
    for (int i = t; i < 8 * 128; i += 256) {
        int sg = i >> 7, c = i & 127;
        int g = g0 + sg;
        if (g <= gmax) {
            float v = spool[sg][c];
            if (v != 0.f) atomicAdd(&pooled[(long long)g * 128 + c], v);
        }
    }
}

// ---------------- classifier: one wave per graph ----------------
__global__ __launch_bounds__(64) void head_kernel(
    const float* __restrict__ pooled, const float* __restrict__ W2b,
    const float* __restrict__ b2b, const float* __restrict__ W3,
    const float* __restrict__ b3, float* __restrict__ out) {
    int g = blockIdx.x;
    int k = threadIdx.x;
    const float* p0 = pooled + (long long)g * 128;
    float acc = b2b[k];
    for (int j = 0; j < 128; j += 4) {
        float4 pv = *(const float4*)&p0[j];
        acc += pv.x * W2b[j * 64 + k] + pv.y * W2b[(j + 1) * 64 + k] +
               pv.z * W2b[(j + 2) * 64 + k] + pv.w * W2b[(j + 3) * 64 + k];
    }
    float h = fmaxf(acc, 0.f);
    float2 w3 = *(const float2*)&W3[k * 2];
    float l0 = h * w3.x;
    float l1 = h * w3.y;
#pragma unroll
    for (int off = 1; off < 64; off <<= 1) {
        l0 += __shfl_xor(l0, off, 64);
        l1 += __shfl_xor(l1, off, 64);
    }
    if (k == 0) {
        l0 += b3[0];
        l1 += b3[1];
        float m = fmaxf(l0, l1);
        float lse = m + logf(expf(l0 - m) + expf(l1 - m));
        out[g * 2 + 0] = l0 - lse;
        out[g * 2 + 1] = l1 - lse;
    }
}

extern "C" void kernel_launch(void* const* d_in, const int* in_sizes, int n_in,
                              void* d_out, int out_size, void* d_ws, size_t ws_size,
                              hipStream_t stream) {
    const float* x     = (const float*)d_in[0];
    const int*   ei    = (const int*)d_in[1];
    const int*   srcI  = ei;
    const int*   dstI  = ei + NE;
    const int*   batch = (const int*)d_in[2];
    const float* W1    = (const float*)d_in[3];
    const float* b1    = (const float*)d_in[4];
    const float* W2    = (const float*)d_in[5];
    const float* b2    = (const float*)d_in[6];
    const float* W3w   = (const float*)d_in[7];
    const float* b3w   = (const float*)d_in[8];
    const float* fc1w  = (const float*)d_in[9];
    const float* fc1b  = (const float*)d_in[10];
    const float* fc2aw = (const float*)d_in[11];
    const float* fc2ab = (const float*)d_in[12];
    const float* fc2bw = (const float*)d_in[13];
    const float* fc2bb = (const float*)d_in[14];
    const float* fc3w  = (const float*)d_in[15];
    const float* fc3b  = (const float*)d_in[16];
    float* out = (float*)d_out;

    // ---- workspace layout ----
    char* p = (char*)d_ws;
    int* pcur = (int*)p;                  p += 2048;
    int* rowptr = (int*)p;                p += (size_t)(NN + 4) * 4;
    int* deg = (int*)p;                   p += (size_t)NN * 4;
    float* dinv = (float*)p;              p += (size_t)NN * 4;
    int* temp = (int*)p;                  p += (size_t)NPART * CAP * 4;  // 16.0 MB
    int* csr_src = (int*)p;               p += (size_t)NPART * CAP * 4;  // 16.0 MB
    uint* tb = (uint*)p;                  p += (size_t)NN * 16 * 4;      // 6.4 MB bf16
    float* x1 = (float*)p;                p += (size_t)NN * 32 * 4;
    float* x2 = (float*)p;                p += (size_t)NN * 32 * 4;
    float* x3 = (float*)p;                p += (size_t)NN * 32 * 4;
    float* pooled = (float*)p;            p += (size_t)NG * 128 * 4;
    float* h64 = (float*)temp;            // alias: temp+csr dead after layer-3 gather

    const int thr = 256;
    int gTile64 = (NN + 63) / 64;
    int gTile128 = (NN + 127) / 128;
    int gGather = (NN * 32 + thr - 1) / thr;
    int gEdge = (NE + CHUNK - 1) / CHUNK;

    // ---- CSR build ----
    zero_misc_kernel<<<(NG * 128 + thr - 1) / thr, thr, 0, stream>>>(pcur, pooled);
    part1_kernel<<<gEdge, thr, 0, stream>>>(srcI, dstI, pcur, temp, NE);
    part2_kernel<<<NPART, thr, 0, stream>>>(temp, pcur, rowptr, deg, dinv, csr_src, NN);

    // ---- conv layers: prescaled bf16 transform -> single fused gather ----
    gemm128_32_direct<<<gTile128, thr, 0, stream>>>(x, W1, dinv, tb, NN);
    gather_kernel<<<gGather, thr, 0, stream>>>(rowptr, deg, csr_src, tb, dinv, b1, x1, NN);

    gemm32_32_kernel<<<gTile128, thr, 0, stream>>>(x1, W2, dinv, tb, NN);
    gather_kernel<<<gGather, thr, 0, stream>>>(rowptr, deg, csr_src, tb, dinv, b2, x2, NN);

    gemm32_32_kernel<<<gTile128, thr, 0, stream>>>(x2, W3w, dinv, tb, NN);
    gather_kernel<<<gGather, thr, 0, stream>>>(rowptr, deg, csr_src, tb, dinv, b3w, x3, NN);

    // ---- MLP head ----
    fc1_tiled_kernel<<<gTile64, thr, 0, stream>>>(x1, x2, x3, fc1w, fc1b, h64, NN);
    fc2a_pool_kernel<<<gTile64, thr, 0, stream>>>(h64, fc2aw, fc2ab, batch, pooled, NN);

    // ---- classifier ----
    head_kernel<<<NG, 64, 0, stream>>>(pooled, fc2bw, fc2bb, fc3w, fc3b, out);
    (void)ws_size; (void)in_sizes; (void)n_in; (void)out_size;
}